// Round 4
// baseline (694.870 us; speedup 1.0000x reference)
//
#include <hip/hip_runtime.h>
#include <math.h>
#include <stdint.h>

#define HIDN  2048
#define NH    16
#define DNOPE 128
#define DROPE 64
#define DQ    192
#define DV    128
#define QRANK 1536
#define KVRANK 512
#define SEQ   1024
#define NBATCH 2
#define NTOK  (NBATCH*SEQ)
#define EPSV  1e-6f

typedef unsigned short u16;
typedef unsigned int   u32;
typedef __attribute__((ext_vector_type(8))) short  short8;   // 8 bf16 (4 VGPRs)
typedef __attribute__((ext_vector_type(8))) unsigned short ushort8;
typedef __attribute__((ext_vector_type(4))) float  f32x4;

__device__ __forceinline__ u16 f2b(float f) {
    u32 u = __float_as_uint(f);
    u = (u + 0x7fffu + ((u >> 16) & 1u)) >> 16;   // RNE
    return (u16)u;
}
__device__ __forceinline__ float b2f(u16 h) {
    return __uint_as_float(((u32)h) << 16);
}

// async global->LDS, 16B per lane; LDS dest = wave-uniform base + lane*16
__device__ __forceinline__ void async_copy16(const u16* g, u16* l) {
    __builtin_amdgcn_global_load_lds(
        (const __attribute__((address_space(1))) u32*)g,
        (__attribute__((address_space(3))) u32*)l,
        16, 0, 0);
}

// ---------------------------------------------------------------------------
// Fused cast fp32 -> bf16 over 10 segments, one dispatch. 8 elems/thread.
// ---------------------------------------------------------------------------
struct CastArgs {
    const float* s[10];
    u16* d[10];
    int cum[11];
};
__global__ __launch_bounds__(256)
void cast_all(CastArgs a, int total_chunks)
{
    int c = blockIdx.x * 256 + threadIdx.x;
    if (c >= total_chunks) return;
    int seg = 0;
    #pragma unroll
    for (int i = 1; i < 10; ++i) seg += (c >= a.cum[i]) ? 1 : 0;
    int local = c - a.cum[seg];
    const float* src = a.s[seg] + (size_t)local * 8;
    u16* dst = a.d[seg] + (size_t)local * 8;
    float4 x = *(const float4*)(src);
    float4 y = *(const float4*)(src + 4);
    ushort8 o;
    o[0]=f2b(x.x); o[1]=f2b(x.y); o[2]=f2b(x.z); o[3]=f2b(x.w);
    o[4]=f2b(y.x); o[5]=f2b(y.y); o[6]=f2b(y.z); o[7]=f2b(y.w);
    *(ushort8*)(dst) = o;
}

// ---------------------------------------------------------------------------
// Multi-segment bf16 MFMA GEMM, m97 staging + LDS double-buffer prefetch.
// C = X[N x K] @ W[M x K]^T, 128x128 tile, BK=32, 4 waves x (64x64).
// stage(kt+1) is issued right AFTER the barrier so the compiler's
// vmcnt(0)-before-barrier drain lands one full compute phase later.
// modes: 0 fp32 flat (ldc) | 5 bf16 flat (ldc) | 1 qf head-major Dh=192
//        3 kv_b split (kf rows stride 192 / V^T) | 4 spqkv triple
// ---------------------------------------------------------------------------
struct GemmSeg {
    const u16* X; const u16* W;
    float* Cf; u16* Cb; u16* Cb2; u16* Cb3;
    int K; int ldx; int ldc; int mode; int bx0;
};
struct GemmArgs { GemmSeg seg[3]; int nseg; };

__global__ __launch_bounds__(256)
void gemm_multi(GemmArgs a)
{
    __shared__ __align__(16) u16 As[2 * 4096];
    __shared__ __align__(16) u16 Bs[2 * 4096];
    int s = 0;
    if (a.nseg > 1 && (int)blockIdx.x >= a.seg[1].bx0) s = 1;
    if (a.nseg > 2 && (int)blockIdx.x >= a.seg[2].bx0) s = 2;
    const GemmSeg g = a.seg[s];

    const int tid = threadIdx.x;
    const int bn = ((int)blockIdx.x - g.bx0) * 128;   // feature base
    const int bm = blockIdx.y * 128;                  // token base
    const int lane = tid & 63, wv = tid >> 6;
    const int lm = lane & 15, lq = lane >> 4;
    const int wm = (wv >> 1) * 64, wn = (wv & 1) * 64;
    const int ldx = g.ldx, K = g.K;
    const u16* Xp = g.X;
    const u16* Wp = g.W;

    auto stage = [&](int kt, int buf) {
        int k0 = kt * 32;
        #pragma unroll
        for (int it = 0; it < 2; ++it) {
            int base = wv * 64 + it * 256;            // wave-uniform chunk base
            int chunk = base + lane;
            int r = chunk >> 2, c = chunk & 3;
            async_copy16(Xp + (size_t)(bm + r) * ldx + k0 + c * 8,
                         As + buf * 4096 + base * 8);
            async_copy16(Wp + (size_t)(bn + r) * K + k0 + c * 8,
                         Bs + buf * 4096 + base * 8);
        }
    };

    f32x4 acc[4][4] = {};
    const int niter = K >> 5;
    stage(0, 0);
    for (int kt = 0; kt < niter; ++kt) {
        int cur = kt & 1;
        __syncthreads();                 // drains stage(kt); frees other buffer
        if (kt + 1 < niter) stage(kt + 1, cur ^ 1);   // overlaps compute below
        const u16* Ab = As + cur * 4096;
        const u16* Bb = Bs + cur * 4096;
        short8 af[4], bf[4];
        #pragma unroll
        for (int mt = 0; mt < 4; ++mt)
            af[mt] = *(const short8*)(Ab + (wm + mt * 16 + lm) * 32 + lq * 8);
        #pragma unroll
        for (int nt = 0; nt < 4; ++nt)
            bf[nt] = *(const short8*)(Bb + (wn + nt * 16 + lm) * 32 + lq * 8);
        #pragma unroll
        for (int mt = 0; mt < 4; ++mt)
            #pragma unroll
            for (int nt = 0; nt < 4; ++nt)
                acc[mt][nt] = __builtin_amdgcn_mfma_f32_16x16x32_bf16(
                    af[mt], bf[nt], acc[mt][nt], 0, 0, 0);
    }

    // epilogue: C/D layout col=lane&15, row=(lane>>4)*4+i  [m89-verified]
    const int mode = g.mode;
    #pragma unroll
    for (int mt = 0; mt < 4; ++mt) {
        int token0 = bm + wm + mt * 16 + lq * 4;
        #pragma unroll
        for (int nt = 0; nt < 4; ++nt) {
            int feat = bn + wn + nt * 16 + lm;
            #pragma unroll
            for (int i = 0; i < 4; ++i) {
                float v = acc[mt][nt][i];
                int tok = token0 + i;
                int b2 = tok >> 10, s2 = tok & (SEQ - 1);
                if (mode == 0) {
                    g.Cf[(size_t)tok * g.ldc + feat] = v;
                } else if (mode == 5) {
                    g.Cb[(size_t)tok * g.ldc + feat] = f2b(v);
                } else if (mode == 1) {
                    int h2 = feat / DQ, d = feat - h2 * DQ;
                    g.Cb[((size_t)((b2 * NH + h2) * SEQ + s2)) * DQ + d] = f2b(v);
                } else if (mode == 3) {
                    int h2 = feat >> 8, c = feat & 255;
                    if (c < 128)
                        g.Cb[((size_t)((b2 * NH + h2) * SEQ + s2)) * DQ + c] = f2b(v);
                    else
                        g.Cb2[((size_t)((b2 * NH + h2) * 128 + (c - 128))) * SEQ + s2] = f2b(v);
                } else { // mode 4: spqkv
                    int wsel = feat >> 11;
                    int f2 = feat & 2047;
                    int h2 = f2 >> 7, d = f2 & 127;
                    if (wsel == 0)
                        g.Cb[((size_t)((b2 * NH + h2) * SEQ + s2)) * 128 + d] = f2b(v);
                    else if (wsel == 1)
                        g.Cb2[((size_t)((b2 * NH + h2) * SEQ + s2)) * 128 + d] = f2b(v);
                    else
                        g.Cb3[((size_t)((b2 * NH + h2) * 128 + d)) * SEQ + s2] = f2b(v);
                }
            }
        }
    }
}

// ---------------------------------------------------------------------------
// Fused RMSNorm, bf16 in-place on amid [tok][3072]:
// rows < NTOK: q_mid cols 0..1535; else kv_lora cols 1536..2047.
// ---------------------------------------------------------------------------
__global__ __launch_bounds__(256)
void rmsnorm_fused(u16* __restrict__ amid, const float* __restrict__ qw,
                   const float* __restrict__ kvw)
{
    int row = blockIdx.x;
    u16* x; const float* w; int D;
    if (row < NTOK) { x = amid + (size_t)row * 3072;            w = qw;  D = QRANK; }
    else            { x = amid + (size_t)(row - NTOK) * 3072 + QRANK; w = kvw; D = KVRANK; }
    float ss = 0.f;
    for (int d = threadIdx.x; d < D; d += 256) { float v = b2f(x[d]); ss += v * v; }
    __shared__ float red[256];
    red[threadIdx.x] = ss;
    __syncthreads();
    for (int off = 128; off > 0; off >>= 1) {
        if (threadIdx.x < off) red[threadIdx.x] += red[threadIdx.x + off];
        __syncthreads();
    }
    float inv = rsqrtf(red[0] / (float)D + EPSV);
    for (int d = threadIdx.x; d < D; d += 256)
        x[d] = f2b(b2f(x[d]) * inv * w[d]);
}

// ---------------------------------------------------------------------------
// Fused RoPE: first 2^20 threads rotate qf in place; next 2^20 threads build
// kf[...,128:192] from amid k_pe (bf16, cols 2048+h*64 of [tok][3072]).
// ---------------------------------------------------------------------------
__global__ __launch_bounds__(256)
void rope_fused(u16* __restrict__ qf, const u16* __restrict__ amid,
                u16* __restrict__ kf)
{
    int t = blockIdx.x * 256 + threadIdx.x;
    bool isq = t < (1 << 20);
    int tt = isq ? t : t - (1 << 20);
    int i = tt & 31, s = (tt >> 5) & (SEQ - 1), bh = tt >> 15;
    float inv_freq = powf(10000.f, -(float)i / 32.f);
    float ang = (float)s * inv_freq;
    float c, sn; sincosf(ang, &sn, &c);
    if (isq) {
        u16* p = qf + ((size_t)bh * SEQ + s) * DQ;
        float x1 = b2f(p[DNOPE + i]), x2 = b2f(p[DNOPE + 32 + i]);
        p[DNOPE + i]      = f2b(x1 * c - x2 * sn);
        p[DNOPE + 32 + i] = f2b(x2 * c + x1 * sn);
    } else {
        int h = bh & (NH - 1), bb = bh >> 4;
        const u16* src = amid + ((size_t)(bb * SEQ + s)) * 3072 + (QRANK + KVRANK) + h * DROPE;
        float x1 = b2f(src[i]), x2 = b2f(src[32 + i]);
        u16* dst = kf + ((size_t)bh * SEQ + s) * DQ + DNOPE;
        dst[i]      = f2b(x1 * c - x2 * sn);
        dst[32 + i] = f2b(x2 * c + x1 * sn);
    }
}

// ---------------------------------------------------------------------------
// MFMA flash attention body. Q,K: [b,h,s,DQK] bf16. Vt: [b,h,d,SEQ] bf16.
// ctx out token-major bf16 [b,s,h*128]. Register prefetch of next K/V tile:
// global loads issued right after the LDS-visible barrier, consumed (LDS
// write) only at the top of the next iteration -> latency overlaps compute.
// ---------------------------------------------------------------------------
template<int DQK>
__device__ __forceinline__
void flash_body(const u16* __restrict__ Q, const u16* __restrict__ Kf,
                const u16* __restrict__ Vt, u16* __restrict__ ctx_out,
                float scale, u16* Ks, u16* Vs, u16* Ps, int qt)
{
    constexpr int KROW = DQK + 8;        // u16 per K row (16B-aligned stride)
    constexpr int CPR  = DQK / 8;        // 16B chunks per K row
    constexpr int NKCH = 32 * CPR / 256; // uint4 per thread for K tile (3 / 2)
    const int tid = threadIdx.x, lane = tid & 63, wv = tid >> 6;
    const int lm = lane & 15, lq = lane >> 4;
    const int h = blockIdx.y, bb = blockIdx.z;
    const size_t bh = (size_t)bb * NH + h;
    const u16* Qb = Q + (bh * SEQ + qt * 64 + wv * 16) * (size_t)DQK;
    const u16* Kb = Kf + bh * SEQ * (size_t)DQK;
    const u16* Vb = Vt + bh * (size_t)128 * SEQ;

    short8 qfrag[DQK / 32];
    #pragma unroll
    for (int ks = 0; ks < DQK / 32; ++ks)
        qfrag[ks] = *(const short8*)(Qb + lm * DQK + ks * 32 + lq * 8);

    uint4 kreg[NKCH], vreg[2];
    auto loadtile = [&](int kt) {
        #pragma unroll
        for (int i = 0; i < NKCH; ++i) {
            int chunk = tid + i * 256;
            int key = chunk / CPR, c = chunk % CPR;
            kreg[i] = *(const uint4*)(Kb + ((size_t)(kt * 32 + key)) * DQK + c * 8);
        }
        #pragma unroll
        for (int i = 0; i < 2; ++i) {
            int chunk = tid + i * 256;
            int d = chunk >> 2, kc = chunk & 3;
            vreg[i] = *(const uint4*)(Vb + (size_t)d * SEQ + kt * 32 + kc * 8);
        }
    };
    auto writetile = [&]() {
        #pragma unroll
        for (int i = 0; i < NKCH; ++i) {
            int chunk = tid + i * 256;
            int key = chunk / CPR, c = chunk % CPR;
            *(uint4*)(Ks + key * KROW + c * 8) = kreg[i];
        }
        #pragma unroll
        for (int i = 0; i < 2; ++i) {
            int chunk = tid + i * 256;
            int d = chunk >> 2, kc = chunk & 3;
            *(uint4*)(Vs + d * 40 + kc * 8) = vreg[i];
        }
    };

    float m_i[4], l_i[4];
    #pragma unroll
    for (int i = 0; i < 4; ++i) { m_i[i] = -INFINITY; l_i[i] = 0.f; }
    f32x4 oacc[8] = {};

    loadtile(0);
    for (int kt = 0; kt < SEQ / 32; ++kt) {
        __syncthreads();                 // all waves done reading previous tile
        writetile();
        __syncthreads();                 // tile visible
        if (kt + 1 < SEQ / 32) loadtile(kt + 1);   // overlaps compute below

        // scores: S[16x32] = Q(16xDQK) . K^T
        f32x4 sacc[2] = {};
        #pragma unroll
        for (int kb = 0; kb < 2; ++kb)
            #pragma unroll
            for (int ks = 0; ks < DQK / 32; ++ks) {
                short8 kfr = *(const short8*)(Ks + (kb * 16 + lm) * KROW + ks * 32 + lq * 8);
                sacc[kb] = __builtin_amdgcn_mfma_f32_16x16x32_bf16(
                    qfrag[ks], kfr, sacc[kb], 0, 0, 0);
            }

        // online softmax (rows = lq*4+i, cols = kb*16+lm)
        float p0[4], p1[4], alpha[4];
        #pragma unroll
        for (int i = 0; i < 4; ++i) {
            float s0 = sacc[0][i] * scale, s1 = sacc[1][i] * scale;
            float mx = fmaxf(s0, s1);
            mx = fmaxf(mx, __shfl_xor(mx, 1));
            mx = fmaxf(mx, __shfl_xor(mx, 2));
            mx = fmaxf(mx, __shfl_xor(mx, 4));
            mx = fmaxf(mx, __shfl_xor(mx, 8));
            float mnew = fmaxf(m_i[i], mx);
            p0[i] = __expf(s0 - mnew);
            p1[i] = __expf(s1 - mnew);
            float sum = p0[i] + p1[i];
            sum += __shfl_xor(sum, 1);
            sum += __shfl_xor(sum, 2);
            sum += __shfl_xor(sum, 4);
            sum += __shfl_xor(sum, 8);
            alpha[i] = __expf(m_i[i] - mnew);
            l_i[i] = l_i[i] * alpha[i] + sum;
            m_i[i] = mnew;
        }

        // P: C-layout -> A-layout via per-wave LDS (wave-local, no barrier)
        u16* Pw = Ps + wv * 640;
        #pragma unroll
        for (int i = 0; i < 4; ++i) {
            Pw[(lq * 4 + i) * 40 + lm]      = f2b(p0[i]);
            Pw[(lq * 4 + i) * 40 + 16 + lm] = f2b(p1[i]);
        }
        short8 pfrag = *(const short8*)(Pw + lm * 40 + lq * 8);

        // O += P . V  (8 col-tiles of 16)
        #pragma unroll
        for (int nt = 0; nt < 8; ++nt) {
            #pragma unroll
            for (int i = 0; i < 4; ++i) oacc[nt][i] *= alpha[i];
            short8 vfr = *(const short8*)(Vs + (nt * 16 + lm) * 40 + lq * 8);
            oacc[nt] = __builtin_amdgcn_mfma_f32_16x16x32_bf16(
                pfrag, vfr, oacc[nt], 0, 0, 0);
        }
    }

    int s0 = qt * 64 + wv * 16 + lq * 4;
    #pragma unroll
    for (int i = 0; i < 4; ++i) {
        float inv = 1.f / l_i[i];
        u16* dst = ctx_out + ((size_t)(bb * SEQ + s0 + i) * NH + h) * 128;
        #pragma unroll
        for (int nt = 0; nt < 8; ++nt)
            dst[nt * 16 + lm] = f2b(oacc[nt][i] * inv);
    }
}

// Fused dual-branch flash: blockIdx.x<16 -> main (DQK=192), else pattern (128)
__global__ __launch_bounds__(256, 4)
void flash_fused(const u16* qf, const u16* kf, const u16* Vtg, u16* ctx,
                 const u16* pq, const u16* pk, const u16* pvt, u16* p_ctx,
                 float scale_main, float scale_pat)
{
    __shared__ __align__(16) u16 Ks[32 * 200];   // sized for DQK=192
    __shared__ __align__(16) u16 Vs[128 * 40];
    __shared__ __align__(16) u16 Ps[4 * 16 * 40];
    if (blockIdx.x < 16)
        flash_body<DQ>(qf, kf, Vtg, ctx, scale_main, Ks, Vs, Ps, blockIdx.x);
    else
        flash_body<128>(pq, pk, pvt, p_ctx, scale_pat, Ks, Vs, Ps, blockIdx.x - 16);
}

// ---------------------------------------------------------------------------
// Gate + combine (fp32): out = g0*main + g1*pattern
// ---------------------------------------------------------------------------
__global__ __launch_bounds__(256)
void gate_combine(const float* __restrict__ x, const float* __restrict__ gw,
                  const float* __restrict__ gb,
                  const float* __restrict__ mo, const float* __restrict__ po,
                  float* __restrict__ out)
{
    const int tok = blockIdx.x;
    const float* xr = x + (size_t)tok * HIDN;
    float d0 = 0.f, d1 = 0.f;
    for (int i = threadIdx.x; i < HIDN; i += 256) {
        float v = xr[i];
        d0 += v * gw[i];
        d1 += v * gw[HIDN + i];
    }
    __shared__ float r0[256], r1[256];
    r0[threadIdx.x] = d0; r1[threadIdx.x] = d1;
    __syncthreads();
    for (int off = 128; off > 0; off >>= 1) {
        if (threadIdx.x < off) {
            r0[threadIdx.x] += r0[threadIdx.x + off];
            r1[threadIdx.x] += r1[threadIdx.x + off];
        }
        __syncthreads();
    }
    float l0 = r0[0] + gb[0], l1 = r1[0] + gb[1];
    float m = fmaxf(l0, l1);
    float e0 = __expf(l0 - m), e1 = __expf(l1 - m);
    float g0 = e0 / (e0 + e1), g1 = e1 / (e0 + e1);
    const float* mr = mo + (size_t)tok * HIDN;
    const float* pr = po + (size_t)tok * HIDN;
    float* orow = out + (size_t)tok * HIDN;
    for (int i = threadIdx.x; i < HIDN; i += 256)
        orow[i] = g0 * mr[i] + g1 * pr[i];
}

// ---------------------------------------------------------------------------
extern "C" void kernel_launch(void* const* d_in, const int* in_sizes, int n_in,
                              void* d_out, int out_size, void* d_ws, size_t ws_size,
                              hipStream_t stream)
{
    const float* X        = (const float*)d_in[0];
    const float* q_a_w    = (const float*)d_in[1];
    const float* q_a_ln_w = (const float*)d_in[2];
    const float* q_b_w    = (const float*)d_in[3];
    const float* kv_a_w   = (const float*)d_in[4];
    const float* kv_a_ln_w= (const float*)d_in[5];
    const float* kv_b_w   = (const float*)d_in[6];
    const float* o_w      = (const float*)d_in[7];
    const float* sp_q_w   = (const float*)d_in[8];
    const float* sp_k_w   = (const float*)d_in[9];
    const float* sp_v_w   = (const float*)d_in[10];
    const float* sp_o_w   = (const float*)d_in[11];
    const float* gate_w   = (const float*)d_in[12];
    const float* gate_b   = (const float*)d_in[13];
    float* out = (float*)d_out;

    // workspace carve (256B aligned) — ~139.5 MB total
    char* p = (char*)d_ws;
    auto alloc = [&](size_t bytes) -> char* {
        char* r = p; p += (bytes + 255) & ~(size_t)255; return r;
    };
    u16* amid      = (u16*)alloc((size_t)NTOK * 3072 * 2);       // bf16 [tok][q_mid|kv_a]
    u16* Xb        = (u16*)alloc((size_t)NTOK * HIDN * 2);
    u16* aw_b      = (u16*)alloc((size_t)3072 * HIDN * 2);       // [q_a_w; kv_a_w]
    u16* q_b_wb    = (u16*)alloc((size_t)NH * DQ * QRANK * 2);
    u16* kv_b_wb   = (u16*)alloc((size_t)NH * 256 * KVRANK * 2);
    u16* o_wb      = (u16*)alloc((size_t)HIDN * HIDN * 2);
    u16* spqkv_wb  = (u16*)alloc((size_t)3 * HIDN * HIDN * 2);   // [spq;spk;spv]
    u16* sp_o_wb   = (u16*)alloc((size_t)HIDN * HIDN * 2);
    u16* qf        = (u16*)alloc((size_t)NTOK * NH * DQ * 2);
    u16* kf        = (u16*)alloc((size_t)NTOK * NH * DQ * 2);
    u16* Vtg       = (u16*)alloc((size_t)NBATCH * NH * 128 * SEQ * 2);
    u16* pq        = (u16*)alloc((size_t)NTOK * HIDN * 2);
    u16* pk        = (u16*)alloc((size_t)NTOK * HIDN * 2);
    // aliases (stream-ordered disjoint lifetimes):
    u16* pvt    = aw_b;          // aw_b dead after amid GEMM; pvt written disp 4
    u16* ctx    = q_b_wb;        // q_b_wb dead after disp 4; ctx written disp 6
    u16* p_ctx  = spqkv_wb;      // spqkv_wb dead after disp 4; written disp 6
    float* patout = (float*)qf;  // qf+kf (25.2MB contig) dead after flash; 16.8MB

    dim3 blk(256);

    // ---- 1. single fused cast dispatch ----
    CastArgs ca;
    const float* srcs[10] = {X, q_a_w, kv_a_w, q_b_w, kv_b_w, o_w,
                             sp_q_w, sp_k_w, sp_v_w, sp_o_w};
    u16* dsts[10] = {Xb, aw_b, aw_b + (size_t)QRANK * HIDN, q_b_wb, kv_b_wb, o_wb,
                     spqkv_wb, spqkv_wb + (size_t)HIDN * HIDN,
                     spqkv_wb + (size_t)2 * HIDN * HIDN, sp_o_wb};
    int ns[10] = {NTOK * HIDN, QRANK * HIDN, 1536 * HIDN, NH * DQ * QRANK,
                  NH * 256 * KVRANK, HIDN * HIDN, HIDN * HIDN, HIDN * HIDN,
                  HIDN * HIDN, HIDN * HIDN};
    int cum = 0;
    for (int i = 0; i < 10; ++i) {
        ca.s[i] = srcs[i]; ca.d[i] = dsts[i];
        ca.cum[i] = cum; cum += ns[i] / 8;
    }
    ca.cum[10] = cum;
    cast_all<<<dim3((cum + 255) / 256), blk, 0, stream>>>(ca, cum);

    // ---- 2. fused q_a + kv_a projection -> amid bf16 [tok][3072] ----
    {
        GemmArgs ga = {};
        ga.nseg = 1;
        ga.seg[0] = {Xb, aw_b, nullptr, amid, nullptr, nullptr,
                     HIDN, HIDN, 3072, 5, 0};
        gemm_multi<<<dim3(24, 16), blk, 0, stream>>>(ga);
    }

    // ---- 3. fused rmsnorm (q_mid rows then kv_lora rows), in place ----
    rmsnorm_fused<<<dim3(2 * NTOK), blk, 0, stream>>>(amid, q_a_ln_w, kv_a_ln_w);

    // ---- 4. mega GEMM: q_b | kv_b | sp_qkv  (104 x 16 = 1664 blocks) ----
    {
        GemmArgs ga = {};
        ga.nseg = 3;
        ga.seg[0] = {amid, q_b_wb, nullptr, qf, nullptr, nullptr,
                     QRANK, 3072, 0, 1, 0};
        ga.seg[1] = {amid + QRANK, kv_b_wb, nullptr, kf, Vtg, nullptr,
                     KVRANK, 3072, 0, 3, 24};
        ga.seg[2] = {Xb, spqkv_wb, nullptr, pq, pk, pvt,
                     HIDN, HIDN, 0, 4, 56};
        gemm_multi<<<dim3(104, 16), blk, 0, stream>>>(ga);
    }

    // ---- 5. fused rope (q in place; k_pe -> kf) ----
    rope_fused<<<dim3(8192), blk, 0, stream>>>(qf, amid, kf);

    // ---- 6. fused dual flash attention (1024 blocks) ----
    flash_fused<<<dim3(32, NH, NBATCH), blk, 0, stream>>>(
        qf, kf, Vtg, ctx, pq, pk, pvt, p_ctx,
        1.0f / sqrtf((float)DQ), 1.0f / sqrtf(128.0f));

    // ---- 7. fused o-proj + sp_o-proj (512 blocks) ----
    {
        GemmArgs ga = {};
        ga.nseg = 2;
        ga.seg[0] = {ctx, o_wb, out, nullptr, nullptr, nullptr,
                     HIDN, HIDN, HIDN, 0, 0};
        ga.seg[1] = {p_ctx, sp_o_wb, patout, nullptr, nullptr, nullptr,
                     HIDN, HIDN, HIDN, 0, 16};
        gemm_multi<<<dim3(32, 16), blk, 0, stream>>>(ga);
    }

    // ---- 8. gate + combine ----
    gate_combine<<<dim3(NTOK), blk, 0, stream>>>(X, gate_w, gate_b, out, patout, out);
}

// Round 5
// 612.031 us; speedup vs baseline: 1.1354x; 1.1354x over previous
//
#include <hip/hip_runtime.h>
#include <math.h>
#include <stdint.h>

#define HIDN  2048
#define NH    16
#define DNOPE 128
#define DROPE 64
#define DQ    192
#define DV    128
#define QRANK 1536
#define KVRANK 512
#define SEQ   1024
#define NBATCH 2
#define NTOK  (NBATCH*SEQ)
#define EPSV  1e-6f

typedef unsigned short u16;
typedef unsigned int   u32;
typedef __attribute__((ext_vector_type(8))) short  short8;   // 8 bf16 (4 VGPRs)
typedef __attribute__((ext_vector_type(8))) unsigned short ushort8;
typedef __attribute__((ext_vector_type(4))) float  f32x4;

__device__ __forceinline__ u16 f2b(float f) {
    u32 u = __float_as_uint(f);
    u = (u + 0x7fffu + ((u >> 16) & 1u)) >> 16;   // RNE
    return (u16)u;
}
__device__ __forceinline__ float b2f(u16 h) {
    return __uint_as_float(((u32)h) << 16);
}

// async global->LDS, 16B per lane; LDS dest = wave-uniform base + lane*16
__device__ __forceinline__ void async_copy16(const u16* g, u16* l) {
    __builtin_amdgcn_global_load_lds(
        (const __attribute__((address_space(1))) u32*)g,
        (__attribute__((address_space(3))) u32*)l,
        16, 0, 0);
}

// ---------------------------------------------------------------------------
// Fused cast fp32 -> bf16 over 10 segments, one dispatch. 8 elems/thread.
// ---------------------------------------------------------------------------
struct CastArgs {
    const float* s[10];
    u16* d[10];
    int cum[11];
};
__global__ __launch_bounds__(256)
void cast_all(CastArgs a, int total_chunks)
{
    int c = blockIdx.x * 256 + threadIdx.x;
    if (c >= total_chunks) return;
    int seg = 0;
    #pragma unroll
    for (int i = 1; i < 10; ++i) seg += (c >= a.cum[i]) ? 1 : 0;
    int local = c - a.cum[seg];
    const float* src = a.s[seg] + (size_t)local * 8;
    u16* dst = a.d[seg] + (size_t)local * 8;
    float4 x = *(const float4*)(src);
    float4 y = *(const float4*)(src + 4);
    ushort8 o;
    o[0]=f2b(x.x); o[1]=f2b(x.y); o[2]=f2b(x.z); o[3]=f2b(x.w);
    o[4]=f2b(y.x); o[5]=f2b(y.y); o[6]=f2b(y.z); o[7]=f2b(y.w);
    *(ushort8*)(dst) = o;
}

// ---------------------------------------------------------------------------
// Multi-segment bf16 MFMA GEMM, m97 staging + LDS double-buffer prefetch.
// C = X[N x K] @ W[M x K]^T, 128x128 tile, BK=32, 4 waves x (64x64).
// stage(kt+1) issued right AFTER the barrier so the vmcnt(0)-before-barrier
// drain lands one full compute phase later.
// modes: 0 fp32 flat (ldc) | 5 bf16 flat (ldc) | 1 qf head-major Dh=192
//        3 kv_b split (kf rows stride 192 / V^T) | 4 spqkv triple
// ---------------------------------------------------------------------------
struct GemmSeg {
    const u16* X; const u16* W;
    float* Cf; u16* Cb; u16* Cb2; u16* Cb3;
    int K; int ldx; int ldc; int mode; int bx0;
};
struct GemmArgs { GemmSeg seg[3]; int nseg; };

__global__ __launch_bounds__(256)
void gemm_multi(GemmArgs a)
{
    __shared__ __align__(16) u16 As[2 * 4096];
    __shared__ __align__(16) u16 Bs[2 * 4096];
    int s = 0;
    if (a.nseg > 1 && (int)blockIdx.x >= a.seg[1].bx0) s = 1;
    if (a.nseg > 2 && (int)blockIdx.x >= a.seg[2].bx0) s = 2;
    const GemmSeg g = a.seg[s];

    const int tid = threadIdx.x;
    const int bn = ((int)blockIdx.x - g.bx0) * 128;   // feature base
    const int bm = blockIdx.y * 128;                  // token base
    const int lane = tid & 63, wv = tid >> 6;
    const int lm = lane & 15, lq = lane >> 4;
    const int wm = (wv >> 1) * 64, wn = (wv & 1) * 64;
    const int ldx = g.ldx, K = g.K;
    const u16* Xp = g.X;
    const u16* Wp = g.W;

    auto stage = [&](int kt, int buf) {
        int k0 = kt * 32;
        #pragma unroll
        for (int it = 0; it < 2; ++it) {
            int base = wv * 64 + it * 256;            // wave-uniform chunk base
            int chunk = base + lane;
            int r = chunk >> 2, c = chunk & 3;
            async_copy16(Xp + (size_t)(bm + r) * ldx + k0 + c * 8,
                         As + buf * 4096 + base * 8);
            async_copy16(Wp + (size_t)(bn + r) * K + k0 + c * 8,
                         Bs + buf * 4096 + base * 8);
        }
    };

    f32x4 acc[4][4] = {};
    const int niter = K >> 5;
    stage(0, 0);
    for (int kt = 0; kt < niter; ++kt) {
        int cur = kt & 1;
        __syncthreads();                 // drains stage(kt); frees other buffer
        if (kt + 1 < niter) stage(kt + 1, cur ^ 1);   // overlaps compute below
        const u16* Ab = As + cur * 4096;
        const u16* Bb = Bs + cur * 4096;
        short8 af[4], bf[4];
        #pragma unroll
        for (int mt = 0; mt < 4; ++mt)
            af[mt] = *(const short8*)(Ab + (wm + mt * 16 + lm) * 32 + lq * 8);
        #pragma unroll
        for (int nt = 0; nt < 4; ++nt)
            bf[nt] = *(const short8*)(Bb + (wn + nt * 16 + lm) * 32 + lq * 8);
        #pragma unroll
        for (int mt = 0; mt < 4; ++mt)
            #pragma unroll
            for (int nt = 0; nt < 4; ++nt)
                acc[mt][nt] = __builtin_amdgcn_mfma_f32_16x16x32_bf16(
                    af[mt], bf[nt], acc[mt][nt], 0, 0, 0);
    }

    // epilogue: C/D layout col=lane&15, row=(lane>>4)*4+i  [m89-verified]
    const int mode = g.mode;
    #pragma unroll
    for (int mt = 0; mt < 4; ++mt) {
        int token0 = bm + wm + mt * 16 + lq * 4;
        #pragma unroll
        for (int nt = 0; nt < 4; ++nt) {
            int feat = bn + wn + nt * 16 + lm;
            #pragma unroll
            for (int i = 0; i < 4; ++i) {
                float v = acc[mt][nt][i];
                int tok = token0 + i;
                int b2 = tok >> 10, s2 = tok & (SEQ - 1);
                if (mode == 0) {
                    g.Cf[(size_t)tok * g.ldc + feat] = v;
                } else if (mode == 5) {
                    g.Cb[(size_t)tok * g.ldc + feat] = f2b(v);
                } else if (mode == 1) {
                    int h2 = feat / DQ, d = feat - h2 * DQ;
                    g.Cb[((size_t)((b2 * NH + h2) * SEQ + s2)) * DQ + d] = f2b(v);
                } else if (mode == 3) {
                    int h2 = feat >> 8, c = feat & 255;
                    if (c < 128)
                        g.Cb[((size_t)((b2 * NH + h2) * SEQ + s2)) * DQ + c] = f2b(v);
                    else
                        g.Cb2[((size_t)((b2 * NH + h2) * 128 + (c - 128))) * SEQ + s2] = f2b(v);
                } else { // mode 4: spqkv
                    int wsel = feat >> 11;
                    int f2 = feat & 2047;
                    int h2 = f2 >> 7, d = f2 & 127;
                    if (wsel == 0)
                        g.Cb[((size_t)((b2 * NH + h2) * SEQ + s2)) * 128 + d] = f2b(v);
                    else if (wsel == 1)
                        g.Cb2[((size_t)((b2 * NH + h2) * SEQ + s2)) * 128 + d] = f2b(v);
                    else
                        g.Cb3[((size_t)((b2 * NH + h2) * 128 + d)) * SEQ + s2] = f2b(v);
                }
            }
        }
    }
}

// ---------------------------------------------------------------------------
// Fused RMSNorm, bf16 in-place on amid [tok][3072]:
// rows < NTOK: q_mid cols 0..1535; else kv_lora cols 1536..2047.
// ---------------------------------------------------------------------------
__global__ __launch_bounds__(256)
void rmsnorm_fused(u16* __restrict__ amid, const float* __restrict__ qw,
                   const float* __restrict__ kvw)
{
    int row = blockIdx.x;
    u16* x; const float* w; int D;
    if (row < NTOK) { x = amid + (size_t)row * 3072;            w = qw;  D = QRANK; }
    else            { x = amid + (size_t)(row - NTOK) * 3072 + QRANK; w = kvw; D = KVRANK; }
    float ss = 0.f;
    for (int d = threadIdx.x; d < D; d += 256) { float v = b2f(x[d]); ss += v * v; }
    __shared__ float red[256];
    red[threadIdx.x] = ss;
    __syncthreads();
    for (int off = 128; off > 0; off >>= 1) {
        if (threadIdx.x < off) red[threadIdx.x] += red[threadIdx.x + off];
        __syncthreads();
    }
    float inv = rsqrtf(red[0] / (float)D + EPSV);
    for (int d = threadIdx.x; d < D; d += 256)
        x[d] = f2b(b2f(x[d]) * inv * w[d]);
}

// ---------------------------------------------------------------------------
// Fused RoPE: first 2^20 threads rotate qf in place; next 2^20 threads build
// kf[...,128:192] from amid k_pe (bf16, cols 2048+h*64 of [tok][3072]).
// ---------------------------------------------------------------------------
__global__ __launch_bounds__(256)
void rope_fused(u16* __restrict__ qf, const u16* __restrict__ amid,
                u16* __restrict__ kf)
{
    int t = blockIdx.x * 256 + threadIdx.x;
    bool isq = t < (1 << 20);
    int tt = isq ? t : t - (1 << 20);
    int i = tt & 31, s = (tt >> 5) & (SEQ - 1), bh = tt >> 15;
    float inv_freq = powf(10000.f, -(float)i / 32.f);
    float ang = (float)s * inv_freq;
    float c, sn; sincosf(ang, &sn, &c);
    if (isq) {
        u16* p = qf + ((size_t)bh * SEQ + s) * DQ;
        float x1 = b2f(p[DNOPE + i]), x2 = b2f(p[DNOPE + 32 + i]);
        p[DNOPE + i]      = f2b(x1 * c - x2 * sn);
        p[DNOPE + 32 + i] = f2b(x2 * c + x1 * sn);
    } else {
        int h = bh & (NH - 1), bb = bh >> 4;
        const u16* src = amid + ((size_t)(bb * SEQ + s)) * 3072 + (QRANK + KVRANK) + h * DROPE;
        float x1 = b2f(src[i]), x2 = b2f(src[32 + i]);
        u16* dst = kf + ((size_t)bh * SEQ + s) * DQ + DNOPE;
        dst[i]      = f2b(x1 * c - x2 * sn);
        dst[32 + i] = f2b(x2 * c + x1 * sn);
    }
}

// ---------------------------------------------------------------------------
// MFMA flash attention body, async double-buffered K/V staging.
// Q,K: [b,h,s,DQK] bf16. Vt: [b,h,d,SEQ] bf16. ctx token-major bf16.
// LDS layouts (unpadded, 64B row stride -> 2-way/free ds_read_b128):
//   K: per-32k planes  [ks][key(32)][32 u16]   (chunk-contiguous load order)
//   V: [d(128)][32 u16]
// stage(kt+1) issued right after the single barrier -> load latency overlaps
// the whole compute phase; no data VGPRs used (global_load_lds), no spill.
// ---------------------------------------------------------------------------
template<int DQK>
__device__ __forceinline__
void flash_body(const u16* __restrict__ Q, const u16* __restrict__ Kf,
                const u16* __restrict__ Vt, u16* __restrict__ ctx_out,
                float scale, u16* Ks, u16* Vs, u16* Ps, int qt, int h, int bb)
{
    constexpr int KSZ  = 32 * DQK;    // u16 per K buffer
    constexpr int VSZ  = 32 * 128;    // u16 per V buffer
    constexpr int NKIT = DQK / 64;    // async calls per wave for K (3 or 2)
    constexpr int NT   = SEQ / 32;
    const int tid = threadIdx.x, lane = tid & 63, wv = tid >> 6;
    const int lm = lane & 15, lq = lane >> 4;
    const size_t bh = (size_t)bb * NH + h;
    const u16* Qb = Q + (bh * SEQ + qt * 64 + wv * 16) * (size_t)DQK;
    const u16* Kb = Kf + bh * SEQ * (size_t)DQK;
    const u16* Vb = Vt + bh * (size_t)128 * SEQ;

    short8 qfrag[DQK / 32];
    #pragma unroll
    for (int ks = 0; ks < DQK / 32; ++ks)
        qfrag[ks] = *(const short8*)(Qb + lm * DQK + ks * 32 + lq * 8);

    auto stage = [&](int kt, int buf) {
        #pragma unroll
        for (int it = 0; it < NKIT; ++it) {
            int base = it * 256 + wv * 64;            // wave-uniform
            int chunk = base + lane;
            int plane = chunk >> 7, rem = chunk & 127;
            int key = rem >> 2, c = rem & 3;
            async_copy16(Kb + (size_t)(kt * 32 + key) * DQK + plane * 32 + c * 8,
                         Ks + buf * KSZ + base * 8);
        }
        #pragma unroll
        for (int it = 0; it < 2; ++it) {
            int base = it * 256 + wv * 64;
            int chunk = base + lane;
            int d = chunk >> 2, c = chunk & 3;
            async_copy16(Vb + (size_t)d * SEQ + kt * 32 + c * 8,
                         Vs + buf * VSZ + base * 8);
        }
    };

    float m_i[4], l_i[4];
    #pragma unroll
    for (int i = 0; i < 4; ++i) { m_i[i] = -INFINITY; l_i[i] = 0.f; }
    f32x4 oacc[8] = {};

    stage(0, 0);
    for (int kt = 0; kt < NT; ++kt) {
        int cur = kt & 1;
        __syncthreads();                 // drains stage(kt); other buffer free
        if (kt + 1 < NT) stage(kt + 1, cur ^ 1);      // overlaps compute below
        const u16* Kc = Ks + cur * KSZ;
        const u16* Vc = Vs + cur * VSZ;

        // scores: S[16x32] = Q(16xDQK) . K^T
        f32x4 sacc[2] = {};
        #pragma unroll
        for (int kb = 0; kb < 2; ++kb)
            #pragma unroll
            for (int ks = 0; ks < DQK / 32; ++ks) {
                short8 kfr = *(const short8*)(Kc + ks * 1024 + (kb * 16 + lm) * 32 + lq * 8);
                sacc[kb] = __builtin_amdgcn_mfma_f32_16x16x32_bf16(
                    qfrag[ks], kfr, sacc[kb], 0, 0, 0);
            }

        // online softmax (rows = lq*4+i, cols = kb*16+lm)
        float p0[4], p1[4], alpha[4];
        #pragma unroll
        for (int i = 0; i < 4; ++i) {
            float s0 = sacc[0][i] * scale, s1 = sacc[1][i] * scale;
            float mx = fmaxf(s0, s1);
            mx = fmaxf(mx, __shfl_xor(mx, 1));
            mx = fmaxf(mx, __shfl_xor(mx, 2));
            mx = fmaxf(mx, __shfl_xor(mx, 4));
            mx = fmaxf(mx, __shfl_xor(mx, 8));
            float mnew = fmaxf(m_i[i], mx);
            p0[i] = __expf(s0 - mnew);
            p1[i] = __expf(s1 - mnew);
            float sum = p0[i] + p1[i];
            sum += __shfl_xor(sum, 1);
            sum += __shfl_xor(sum, 2);
            sum += __shfl_xor(sum, 4);
            sum += __shfl_xor(sum, 8);
            alpha[i] = __expf(m_i[i] - mnew);
            l_i[i] = l_i[i] * alpha[i] + sum;
            m_i[i] = mnew;
        }

        // P: C-layout -> A-layout via per-wave LDS (wave-local, no barrier)
        u16* Pw = Ps + wv * 640;
        #pragma unroll
        for (int i = 0; i < 4; ++i) {
            Pw[(lq * 4 + i) * 40 + lm]      = f2b(p0[i]);
            Pw[(lq * 4 + i) * 40 + 16 + lm] = f2b(p1[i]);
        }
        short8 pfrag = *(const short8*)(Pw + lm * 40 + lq * 8);

        // O += P . V  (8 col-tiles of 16)
        #pragma unroll
        for (int nt = 0; nt < 8; ++nt) {
            #pragma unroll
            for (int i = 0; i < 4; ++i) oacc[nt][i] *= alpha[i];
            short8 vfr = *(const short8*)(Vc + (nt * 16 + lm) * 32 + lq * 8);
            oacc[nt] = __builtin_amdgcn_mfma_f32_16x16x32_bf16(
                pfrag, vfr, oacc[nt], 0, 0, 0);
        }
    }

    int s0 = qt * 64 + wv * 16 + lq * 4;
    #pragma unroll
    for (int i = 0; i < 4; ++i) {
        float inv = 1.f / l_i[i];
        u16* dst = ctx_out + ((size_t)(bb * SEQ + s0 + i) * NH + h) * 128;
        #pragma unroll
        for (int nt = 0; nt < 8; ++nt)
            dst[nt * 16 + lm] = f2b(oacc[nt][i] * inv);
    }
}

// Fused dual-branch flash. Grid (NH, 32, NBATCH): x=h so all q-tiles of a
// head land on one XCD (linear id stride 16 => id%8 const) -> K/V L2 reuse.
__global__ __launch_bounds__(256, 3)
void flash_fused(const u16* qf, const u16* kf, const u16* Vtg, u16* ctx,
                 const u16* pq, const u16* pk, const u16* pvt, u16* p_ctx,
                 float scale_main, float scale_pat)
{
    __shared__ __align__(16) u16 Ks[2 * 32 * DQ];    // 24 KB
    __shared__ __align__(16) u16 Vs[2 * 32 * 128];   // 16 KB
    __shared__ __align__(16) u16 Ps[4 * 16 * 40];    // 5 KB
    int h = blockIdx.x, qtb = blockIdx.y, bb = blockIdx.z;
    if (qtb < 16)
        flash_body<DQ>(qf, kf, Vtg, ctx, scale_main, Ks, Vs, Ps, qtb, h, bb);
    else
        flash_body<128>(pq, pk, pvt, p_ctx, scale_pat, Ks, Vs, Ps, qtb - 16, h, bb);
}

// ---------------------------------------------------------------------------
// Gate + combine (fp32): out = g0*main + g1*pattern
// ---------------------------------------------------------------------------
__global__ __launch_bounds__(256)
void gate_combine(const float* __restrict__ x, const float* __restrict__ gw,
                  const float* __restrict__ gb,
                  const float* __restrict__ mo, const float* __restrict__ po,
                  float* __restrict__ out)
{
    const int tok = blockIdx.x;
    const float* xr = x + (size_t)tok * HIDN;
    float d0 = 0.f, d1 = 0.f;
    for (int i = threadIdx.x; i < HIDN; i += 256) {
        float v = xr[i];
        d0 += v * gw[i];
        d1 += v * gw[HIDN + i];
    }
    __shared__ float r0[256], r1[256];
    r0[threadIdx.x] = d0; r1[threadIdx.x] = d1;
    __syncthreads();
    for (int off = 128; off > 0; off >>= 1) {
        if (threadIdx.x < off) {
            r0[threadIdx.x] += r0[threadIdx.x + off];
            r1[threadIdx.x] += r1[threadIdx.x + off];
        }
        __syncthreads();
    }
    float l0 = r0[0] + gb[0], l1 = r1[0] + gb[1];
    float m = fmaxf(l0, l1);
    float e0 = __expf(l0 - m), e1 = __expf(l1 - m);
    float g0 = e0 / (e0 + e1), g1 = e1 / (e0 + e1);
    const float* mr = mo + (size_t)tok * HIDN;
    const float* pr = po + (size_t)tok * HIDN;
    float* orow = out + (size_t)tok * HIDN;
    for (int i = threadIdx.x; i < HIDN; i += 256)
        orow[i] = g0 * mr[i] + g1 * pr[i];
}

// ---------------------------------------------------------------------------
extern "C" void kernel_launch(void* const* d_in, const int* in_sizes, int n_in,
                              void* d_out, int out_size, void* d_ws, size_t ws_size,
                              hipStream_t stream)
{
    const float* X        = (const float*)d_in[0];
    const float* q_a_w    = (const float*)d_in[1];
    const float* q_a_ln_w = (const float*)d_in[2];
    const float* q_b_w    = (const float*)d_in[3];
    const float* kv_a_w   = (const float*)d_in[4];
    const float* kv_a_ln_w= (const float*)d_in[5];
    const float* kv_b_w   = (const float*)d_in[6];
    const float* o_w      = (const float*)d_in[7];
    const float* sp_q_w   = (const float*)d_in[8];
    const float* sp_k_w   = (const float*)d_in[9];
    const float* sp_v_w   = (const float*)d_in[10];
    const float* sp_o_w   = (const float*)d_in[11];
    const float* gate_w   = (const float*)d_in[12];
    const float* gate_b   = (const float*)d_in[13];
    float* out = (float*)d_out;

    // workspace carve (256B aligned) — ~139.5 MB total
    char* p = (char*)d_ws;
    auto alloc = [&](size_t bytes) -> char* {
        char* r = p; p += (bytes + 255) & ~(size_t)255; return r;
    };
    u16* amid      = (u16*)alloc((size_t)NTOK * 3072 * 2);       // bf16 [tok][q_mid|kv_a]
    u16* Xb        = (u16*)alloc((size_t)NTOK * HIDN * 2);
    u16* aw_b      = (u16*)alloc((size_t)3072 * HIDN * 2);       // [q_a_w; kv_a_w]
    u16* q_b_wb    = (u16*)alloc((size_t)NH * DQ * QRANK * 2);
    u16* kv_b_wb   = (u16*)alloc((size_t)NH * 256 * KVRANK * 2);
    u16* o_wb      = (u16*)alloc((size_t)HIDN * HIDN * 2);
    u16* spqkv_wb  = (u16*)alloc((size_t)3 * HIDN * HIDN * 2);   // [spq;spk;spv]
    u16* sp_o_wb   = (u16*)alloc((size_t)HIDN * HIDN * 2);
    u16* qf        = (u16*)alloc((size_t)NTOK * NH * DQ * 2);
    u16* kf        = (u16*)alloc((size_t)NTOK * NH * DQ * 2);
    u16* Vtg       = (u16*)alloc((size_t)NBATCH * NH * 128 * SEQ * 2);
    u16* pq        = (u16*)alloc((size_t)NTOK * HIDN * 2);
    u16* pk        = (u16*)alloc((size_t)NTOK * HIDN * 2);
    // aliases (stream-ordered disjoint lifetimes):
    u16* pvt    = aw_b;          // aw_b dead after amid GEMM; pvt written disp 4
    u16* ctx    = q_b_wb;        // q_b_wb dead after disp 4; ctx written disp 6
    u16* p_ctx  = spqkv_wb;      // spqkv_wb dead after disp 4; written disp 6
    float* patout = (float*)qf;  // qf+kf (25.2MB contig) dead after flash; 16.8MB

    dim3 blk(256);

    // ---- 1. single fused cast dispatch ----
    CastArgs ca;
    const float* srcs[10] = {X, q_a_w, kv_a_w, q_b_w, kv_b_w, o_w,
                             sp_q_w, sp_k_w, sp_v_w, sp_o_w};
    u16* dsts[10] = {Xb, aw_b, aw_b + (size_t)QRANK * HIDN, q_b_wb, kv_b_wb, o_wb,
                     spqkv_wb, spqkv_wb + (size_t)HIDN * HIDN,
                     spqkv_wb + (size_t)2 * HIDN * HIDN, sp_o_wb};
    int ns[10] = {NTOK * HIDN, QRANK * HIDN, 1536 * HIDN, NH * DQ * QRANK,
                  NH * 256 * KVRANK, HIDN * HIDN, HIDN * HIDN, HIDN * HIDN,
                  HIDN * HIDN, HIDN * HIDN};
    int cum = 0;
    for (int i = 0; i < 10; ++i) {
        ca.s[i] = srcs[i]; ca.d[i] = dsts[i];
        ca.cum[i] = cum; cum += ns[i] / 8;
    }
    ca.cum[10] = cum;
    cast_all<<<dim3((cum + 255) / 256), blk, 0, stream>>>(ca, cum);

    // ---- 2. fused q_a + kv_a projection -> amid bf16 [tok][3072] ----
    {
        GemmArgs ga = {};
        ga.nseg = 1;
        ga.seg[0] = {Xb, aw_b, nullptr, amid, nullptr, nullptr,
                     HIDN, HIDN, 3072, 5, 0};
        gemm_multi<<<dim3(24, 16), blk, 0, stream>>>(ga);
    }

    // ---- 3. fused rmsnorm (q_mid rows then kv_lora rows), in place ----
    rmsnorm_fused<<<dim3(2 * NTOK), blk, 0, stream>>>(amid, q_a_ln_w, kv_a_ln_w);

    // ---- 4. mega GEMM: q_b | kv_b | sp_qkv  (104 x 16 = 1664 blocks) ----
    {
        GemmArgs ga = {};
        ga.nseg = 3;
        ga.seg[0] = {amid, q_b_wb, nullptr, qf, nullptr, nullptr,
                     QRANK, 3072, 0, 1, 0};
        ga.seg[1] = {amid + QRANK, kv_b_wb, nullptr, kf, Vtg, nullptr,
                     KVRANK, 3072, 0, 3, 24};
        ga.seg[2] = {Xb, spqkv_wb, nullptr, pq, pk, pvt,
                     HIDN, HIDN, 0, 4, 56};
        gemm_multi<<<dim3(104, 16), blk, 0, stream>>>(ga);
    }

    // ---- 5. fused rope (q in place; k_pe -> kf) ----
    rope_fused<<<dim3(8192), blk, 0, stream>>>(qf, amid, kf);

    // ---- 6. fused dual flash attention (1024 blocks, XCD-swizzled) ----
    flash_fused<<<dim3(NH, 32, NBATCH), blk, 0, stream>>>(
        qf, kf, Vtg, ctx, pq, pk, pvt, p_ctx,
        1.0f / sqrtf((float)DQ), 1.0f / sqrtf(128.0f));

    // ---- 7. fused o-proj + sp_o-proj (512 blocks) ----
    {
        GemmArgs ga = {};
        ga.nseg = 2;
        ga.seg[0] = {ctx, o_wb, out, nullptr, nullptr, nullptr,
                     HIDN, HIDN, HIDN, 0, 0};
        ga.seg[1] = {p_ctx, sp_o_wb, patout, nullptr, nullptr, nullptr,
                     HIDN, HIDN, HIDN, 0, 16};
        gemm_multi<<<dim3(32, 16), blk, 0, stream>>>(ga);
    }

    // ---- 8. gate + combine ----
    gate_combine<<<dim3(NTOK), blk, 0, stream>>>(X, gate_w, gate_b, out, patout, out);
}

// Round 6
// 601.919 us; speedup vs baseline: 1.1544x; 1.0168x over previous
//
#include <hip/hip_runtime.h>
#include <math.h>
#include <stdint.h>

#define HIDN  2048
#define NH    16
#define DNOPE 128
#define DROPE 64
#define DQ    192
#define DV    128
#define QRANK 1536
#define KVRANK 512
#define SEQ   1024
#define NBATCH 2
#define NTOK  (NBATCH*SEQ)
#define EPSV  1e-6f

typedef unsigned short u16;
typedef unsigned int   u32;
typedef __attribute__((ext_vector_type(8))) short  short8;   // 8 bf16 (4 VGPRs)
typedef __attribute__((ext_vector_type(8))) unsigned short ushort8;
typedef __attribute__((ext_vector_type(4))) float  f32x4;

__device__ __forceinline__ u16 f2b(float f) {
    u32 u = __float_as_uint(f);
    u = (u + 0x7fffu + ((u >> 16) & 1u)) >> 16;   // RNE
    return (u16)u;
}
__device__ __forceinline__ float b2f(u16 h) {
    return __uint_as_float(((u32)h) << 16);
}

// async global->LDS, 16B per lane; LDS dest = wave-uniform base + lane*16
__device__ __forceinline__ void async_copy16(const u16* g, u16* l) {
    __builtin_amdgcn_global_load_lds(
        (const __attribute__((address_space(1))) u32*)g,
        (__attribute__((address_space(3))) u32*)l,
        16, 0, 0);
}

// LDS bank swizzle: slot for (row r, 16B-chunk c) = r*4 + (c ^ ((r>>1)&3)).
// 16 consecutive rows at fixed c then span all 32 banks 2-way (free, m136);
// unswizzled 64B-stride rows pile 8 lanes on one 4-bank group (~4 cyc/read,
// = the 9.7M SQ_LDS_BANK_CONFLICT seen in R5's mega GEMM).
__device__ __forceinline__ int swz(int r, int c) { return r * 4 + (c ^ ((r >> 1) & 3)); }

// ---------------------------------------------------------------------------
// Fused cast fp32 -> bf16 over 10 segments, one dispatch. 8 elems/thread.
// ---------------------------------------------------------------------------
struct CastArgs {
    const float* s[10];
    u16* d[10];
    int cum[11];
};
__global__ __launch_bounds__(256)
void cast_all(CastArgs a, int total_chunks)
{
    int c = blockIdx.x * 256 + threadIdx.x;
    if (c >= total_chunks) return;
    int seg = 0;
    #pragma unroll
    for (int i = 1; i < 10; ++i) seg += (c >= a.cum[i]) ? 1 : 0;
    int local = c - a.cum[seg];
    const float* src = a.s[seg] + (size_t)local * 8;
    u16* dst = a.d[seg] + (size_t)local * 8;
    float4 x = *(const float4*)(src);
    float4 y = *(const float4*)(src + 4);
    ushort8 o;
    o[0]=f2b(x.x); o[1]=f2b(x.y); o[2]=f2b(x.z); o[3]=f2b(x.w);
    o[4]=f2b(y.x); o[5]=f2b(y.y); o[6]=f2b(y.z); o[7]=f2b(y.w);
    *(ushort8*)(dst) = o;
}

// ---------------------------------------------------------------------------
// Multi-segment bf16 MFMA GEMM, m97 staging + LDS double-buffer prefetch +
// bank swizzle. C = X[N x K] @ W[M x K]^T, 128x128 tile, BK=32, 4 waves.
// modes: 0 fp32 flat (ldc) | 5 bf16 flat (ldc) | 1 qf head-major Dh=192
//        3 kv_b split (kf rows stride 192 / V^T) | 4 spqkv triple
// ---------------------------------------------------------------------------
struct GemmSeg {
    const u16* X; const u16* W;
    float* Cf; u16* Cb; u16* Cb2; u16* Cb3;
    int K; int ldx; int ldc; int mode; int bx0;
};
struct GemmArgs { GemmSeg seg[3]; int nseg; };

__global__ __launch_bounds__(256)
void gemm_multi(GemmArgs a)
{
    __shared__ __align__(16) u16 As[2 * 4096];
    __shared__ __align__(16) u16 Bs[2 * 4096];
    int s = 0;
    if (a.nseg > 1 && (int)blockIdx.x >= a.seg[1].bx0) s = 1;
    if (a.nseg > 2 && (int)blockIdx.x >= a.seg[2].bx0) s = 2;
    const GemmSeg g = a.seg[s];

    const int tid = threadIdx.x;
    const int bn = ((int)blockIdx.x - g.bx0) * 128;   // feature base
    const int bm = blockIdx.y * 128;                  // token base
    const int lane = tid & 63, wv = tid >> 6;
    const int lm = lane & 15, lq = lane >> 4;
    const int wm = (wv >> 1) * 64, wn = (wv & 1) * 64;
    const int ldx = g.ldx, K = g.K;
    const u16* Xp = g.X;
    const u16* Wp = g.W;

    auto stage = [&](int kt, int buf) {
        int k0 = kt * 32;
        #pragma unroll
        for (int it = 0; it < 2; ++it) {
            int base = wv * 64 + it * 256;            // wave-uniform chunk base
            int slot = base + lane;
            int r = slot >> 2, c = (slot & 3) ^ ((r >> 1) & 3);   // swizzle inverse
            async_copy16(Xp + (size_t)(bm + r) * ldx + k0 + c * 8,
                         As + buf * 4096 + base * 8);
            async_copy16(Wp + (size_t)(bn + r) * K + k0 + c * 8,
                         Bs + buf * 4096 + base * 8);
        }
    };

    f32x4 acc[4][4] = {};
    const int niter = K >> 5;
    stage(0, 0);
    for (int kt = 0; kt < niter; ++kt) {
        int cur = kt & 1;
        __syncthreads();                 // drains stage(kt); frees other buffer
        if (kt + 1 < niter) stage(kt + 1, cur ^ 1);   // overlaps compute below
        const u16* Ab = As + cur * 4096;
        const u16* Bb = Bs + cur * 4096;
        short8 af[4], bf[4];
        #pragma unroll
        for (int mt = 0; mt < 4; ++mt) {
            int R = wm + mt * 16 + lm;
            af[mt] = *(const short8*)(Ab + swz(R, lq) * 8);
        }
        #pragma unroll
        for (int nt = 0; nt < 4; ++nt) {
            int R = wn + nt * 16 + lm;
            bf[nt] = *(const short8*)(Bb + swz(R, lq) * 8);
        }
        #pragma unroll
        for (int mt = 0; mt < 4; ++mt)
            #pragma unroll
            for (int nt = 0; nt < 4; ++nt)
                acc[mt][nt] = __builtin_amdgcn_mfma_f32_16x16x32_bf16(
                    af[mt], bf[nt], acc[mt][nt], 0, 0, 0);
    }

    // epilogue: C/D layout col=lane&15, row=(lane>>4)*4+i  [m89-verified]
    const int mode = g.mode;
    #pragma unroll
    for (int mt = 0; mt < 4; ++mt) {
        int token0 = bm + wm + mt * 16 + lq * 4;
        #pragma unroll
        for (int nt = 0; nt < 4; ++nt) {
            int feat = bn + wn + nt * 16 + lm;
            #pragma unroll
            for (int i = 0; i < 4; ++i) {
                float v = acc[mt][nt][i];
                int tok = token0 + i;
                int b2 = tok >> 10, s2 = tok & (SEQ - 1);
                if (mode == 0) {
                    g.Cf[(size_t)tok * g.ldc + feat] = v;
                } else if (mode == 5) {
                    g.Cb[(size_t)tok * g.ldc + feat] = f2b(v);
                } else if (mode == 1) {
                    int h2 = feat / DQ, d = feat - h2 * DQ;
                    g.Cb[((size_t)((b2 * NH + h2) * SEQ + s2)) * DQ + d] = f2b(v);
                } else if (mode == 3) {
                    int h2 = feat >> 8, c = feat & 255;
                    if (c < 128)
                        g.Cb[((size_t)((b2 * NH + h2) * SEQ + s2)) * DQ + c] = f2b(v);
                    else
                        g.Cb2[((size_t)((b2 * NH + h2) * 128 + (c - 128))) * SEQ + s2] = f2b(v);
                } else { // mode 4: spqkv
                    int wsel = feat >> 11;
                    int f2 = feat & 2047;
                    int h2 = f2 >> 7, d = f2 & 127;
                    if (wsel == 0)
                        g.Cb[((size_t)((b2 * NH + h2) * SEQ + s2)) * 128 + d] = f2b(v);
                    else if (wsel == 1)
                        g.Cb2[((size_t)((b2 * NH + h2) * SEQ + s2)) * 128 + d] = f2b(v);
                    else
                        g.Cb3[((size_t)((b2 * NH + h2) * 128 + d)) * SEQ + s2] = f2b(v);
                }
            }
        }
    }
}

// ---------------------------------------------------------------------------
// Fused RMSNorm, bf16 in-place on amid [tok][3072]:
// rows < NTOK: q_mid cols 0..1535; else kv_lora cols 1536..2047.
// ---------------------------------------------------------------------------
__global__ __launch_bounds__(256)
void rmsnorm_fused(u16* __restrict__ amid, const float* __restrict__ qw,
                   const float* __restrict__ kvw)
{
    int row = blockIdx.x;
    u16* x; const float* w; int D;
    if (row < NTOK) { x = amid + (size_t)row * 3072;            w = qw;  D = QRANK; }
    else            { x = amid + (size_t)(row - NTOK) * 3072 + QRANK; w = kvw; D = KVRANK; }
    float ss = 0.f;
    for (int d = threadIdx.x; d < D; d += 256) { float v = b2f(x[d]); ss += v * v; }
    __shared__ float red[256];
    red[threadIdx.x] = ss;
    __syncthreads();
    for (int off = 128; off > 0; off >>= 1) {
        if (threadIdx.x < off) red[threadIdx.x] += red[threadIdx.x + off];
        __syncthreads();
    }
    float inv = rsqrtf(red[0] / (float)D + EPSV);
    for (int d = threadIdx.x; d < D; d += 256)
        x[d] = f2b(b2f(x[d]) * inv * w[d]);
}

// ---------------------------------------------------------------------------
// Fused RoPE: first 2^20 threads rotate qf in place; next 2^20 threads build
// kf[...,128:192] from amid k_pe (bf16, cols 2048+h*64 of [tok][3072]).
// ---------------------------------------------------------------------------
__global__ __launch_bounds__(256)
void rope_fused(u16* __restrict__ qf, const u16* __restrict__ amid,
                u16* __restrict__ kf)
{
    int t = blockIdx.x * 256 + threadIdx.x;
    bool isq = t < (1 << 20);
    int tt = isq ? t : t - (1 << 20);
    int i = tt & 31, s = (tt >> 5) & (SEQ - 1), bh = tt >> 15;
    float inv_freq = powf(10000.f, -(float)i / 32.f);
    float ang = (float)s * inv_freq;
    float c, sn; sincosf(ang, &sn, &c);
    if (isq) {
        u16* p = qf + ((size_t)bh * SEQ + s) * DQ;
        float x1 = b2f(p[DNOPE + i]), x2 = b2f(p[DNOPE + 32 + i]);
        p[DNOPE + i]      = f2b(x1 * c - x2 * sn);
        p[DNOPE + 32 + i] = f2b(x2 * c + x1 * sn);
    } else {
        int h = bh & (NH - 1), bb = bh >> 4;
        const u16* src = amid + ((size_t)(bb * SEQ + s)) * 3072 + (QRANK + KVRANK) + h * DROPE;
        float x1 = b2f(src[i]), x2 = b2f(src[32 + i]);
        u16* dst = kf + ((size_t)bh * SEQ + s) * DQ + DNOPE;
        dst[i]      = f2b(x1 * c - x2 * sn);
        dst[32 + i] = f2b(x2 * c + x1 * sn);
    }
}

// ---------------------------------------------------------------------------
// MFMA flash attention body, async double-buffered K/V staging, bank-swizzled
// LDS. Q,K: [b,h,s,DQK] bf16. Vt: [b,h,d,SEQ] bf16. ctx token-major bf16.
//   K: per-32k planes [ks][swizzled 32x4 chunks]
//   V: [swizzled 128x4 chunks]
// ---------------------------------------------------------------------------
template<int DQK>
__device__ __forceinline__
void flash_body(const u16* __restrict__ Q, const u16* __restrict__ Kf,
                const u16* __restrict__ Vt, u16* __restrict__ ctx_out,
                float scale, u16* Ks, u16* Vs, u16* Ps, int qt, int h, int bb)
{
    constexpr int KSZ  = 32 * DQK;    // u16 per K buffer
    constexpr int VSZ  = 32 * 128;    // u16 per V buffer
    constexpr int NKIT = DQK / 64;    // async calls per wave for K (3 or 2)
    constexpr int NT   = SEQ / 32;
    const int tid = threadIdx.x, lane = tid & 63, wv = tid >> 6;
    const int lm = lane & 15, lq = lane >> 4;
    const size_t bh = (size_t)bb * NH + h;
    const u16* Qb = Q + (bh * SEQ + qt * 64 + wv * 16) * (size_t)DQK;
    const u16* Kb = Kf + bh * SEQ * (size_t)DQK;
    const u16* Vb = Vt + bh * (size_t)128 * SEQ;

    short8 qfrag[DQK / 32];
    #pragma unroll
    for (int ks = 0; ks < DQK / 32; ++ks)
        qfrag[ks] = *(const short8*)(Qb + lm * DQK + ks * 32 + lq * 8);

    auto stage = [&](int kt, int buf) {
        #pragma unroll
        for (int it = 0; it < NKIT; ++it) {
            int base = it * 256 + wv * 64;            // wave-uniform
            int slot = base + lane;
            int plane = slot >> 7, rem = slot & 127;
            int key = rem >> 2, c = (rem & 3) ^ ((key >> 1) & 3);  // swizzle inv
            async_copy16(Kb + (size_t)(kt * 32 + key) * DQK + plane * 32 + c * 8,
                         Ks + buf * KSZ + base * 8);
        }
        #pragma unroll
        for (int it = 0; it < 2; ++it) {
            int base = it * 256 + wv * 64;
            int slot = base + lane;
            int d = slot >> 2, c = (slot & 3) ^ ((d >> 1) & 3);    // swizzle inv
            async_copy16(Vb + (size_t)d * SEQ + kt * 32 + c * 8,
                         Vs + buf * VSZ + base * 8);
        }
    };

    float m_i[4], l_i[4];
    #pragma unroll
    for (int i = 0; i < 4; ++i) { m_i[i] = -INFINITY; l_i[i] = 0.f; }
    f32x4 oacc[8] = {};

    stage(0, 0);
    for (int kt = 0; kt < NT; ++kt) {
        int cur = kt & 1;
        __syncthreads();                 // drains stage(kt); other buffer free
        if (kt + 1 < NT) stage(kt + 1, cur ^ 1);      // overlaps compute below
        const u16* Kc = Ks + cur * KSZ;
        const u16* Vc = Vs + cur * VSZ;

        // scores: S[16x32] = Q(16xDQK) . K^T
        f32x4 sacc[2] = {};
        #pragma unroll
        for (int kb = 0; kb < 2; ++kb)
            #pragma unroll
            for (int ks = 0; ks < DQK / 32; ++ks) {
                int R = kb * 16 + lm;
                short8 kfr = *(const short8*)(Kc + ks * 1024 + swz(R, lq) * 8);
                sacc[kb] = __builtin_amdgcn_mfma_f32_16x16x32_bf16(
                    qfrag[ks], kfr, sacc[kb], 0, 0, 0);
            }

        // online softmax (rows = lq*4+i, cols = kb*16+lm)
        float p0[4], p1[4], alpha[4];
        #pragma unroll
        for (int i = 0; i < 4; ++i) {
            float s0 = sacc[0][i] * scale, s1 = sacc[1][i] * scale;
            float mx = fmaxf(s0, s1);
            mx = fmaxf(mx, __shfl_xor(mx, 1));
            mx = fmaxf(mx, __shfl_xor(mx, 2));
            mx = fmaxf(mx, __shfl_xor(mx, 4));
            mx = fmaxf(mx, __shfl_xor(mx, 8));
            float mnew = fmaxf(m_i[i], mx);
            p0[i] = __expf(s0 - mnew);
            p1[i] = __expf(s1 - mnew);
            float sum = p0[i] + p1[i];
            sum += __shfl_xor(sum, 1);
            sum += __shfl_xor(sum, 2);
            sum += __shfl_xor(sum, 4);
            sum += __shfl_xor(sum, 8);
            alpha[i] = __expf(m_i[i] - mnew);
            l_i[i] = l_i[i] * alpha[i] + sum;
            m_i[i] = mnew;
        }

        // P: C-layout -> A-layout via per-wave LDS (wave-local, no barrier)
        u16* Pw = Ps + wv * 640;
        #pragma unroll
        for (int i = 0; i < 4; ++i) {
            Pw[(lq * 4 + i) * 40 + lm]      = f2b(p0[i]);
            Pw[(lq * 4 + i) * 40 + 16 + lm] = f2b(p1[i]);
        }
        short8 pfrag = *(const short8*)(Pw + lm * 40 + lq * 8);

        // O += P . V  (8 col-tiles of 16)
        #pragma unroll
        for (int nt = 0; nt < 8; ++nt) {
            #pragma unroll
            for (int i = 0; i < 4; ++i) oacc[nt][i] *= alpha[i];
            int R = nt * 16 + lm;
            short8 vfr = *(const short8*)(Vc + swz(R, lq) * 8);
            oacc[nt] = __builtin_amdgcn_mfma_f32_16x16x32_bf16(
                pfrag, vfr, oacc[nt], 0, 0, 0);
        }
    }

    int s0 = qt * 64 + wv * 16 + lq * 4;
    #pragma unroll
    for (int i = 0; i < 4; ++i) {
        float inv = 1.f / l_i[i];
        u16* dst = ctx_out + ((size_t)(bb * SEQ + s0 + i) * NH + h) * 128;
        #pragma unroll
        for (int nt = 0; nt < 8; ++nt)
            dst[nt * 16 + lm] = f2b(oacc[nt][i] * inv);
    }
}

// Fused dual-branch flash. Grid (NH, 32, NBATCH): x=h so all q-tiles of a
// head land on one XCD (linear id stride 16 => id%8 const) -> K/V L2 reuse.
__global__ __launch_bounds__(256, 3)
void flash_fused(const u16* qf, const u16* kf, const u16* Vtg, u16* ctx,
                 const u16* pq, const u16* pk, const u16* pvt, u16* p_ctx,
                 float scale_main, float scale_pat)
{
    __shared__ __align__(16) u16 Ks[2 * 32 * DQ];    // 24 KB
    __shared__ __align__(16) u16 Vs[2 * 32 * 128];   // 16 KB
    __shared__ __align__(16) u16 Ps[4 * 16 * 40];    // 5 KB
    int h = blockIdx.x, qtb = blockIdx.y, bb = blockIdx.z;
    if (qtb < 16)
        flash_body<DQ>(qf, kf, Vtg, ctx, scale_main, Ks, Vs, Ps, qtb, h, bb);
    else
        flash_body<128>(pq, pk, pvt, p_ctx, scale_pat, Ks, Vs, Ps, qtb - 16, h, bb);
}

// ---------------------------------------------------------------------------
// Gate + combine (fp32): out = g0*main + g1*pattern
// ---------------------------------------------------------------------------
__global__ __launch_bounds__(256)
void gate_combine(const float* __restrict__ x, const float* __restrict__ gw,
                  const float* __restrict__ gb,
                  const float* __restrict__ mo, const float* __restrict__ po,
                  float* __restrict__ out)
{
    const int tok = blockIdx.x;
    const float* xr = x + (size_t)tok * HIDN;
    float d0 = 0.f, d1 = 0.f;
    for (int i = threadIdx.x; i < HIDN; i += 256) {
        float v = xr[i];
        d0 += v * gw[i];
        d1 += v * gw[HIDN + i];
    }
    __shared__ float r0[256], r1[256];
    r0[threadIdx.x] = d0; r1[threadIdx.x] = d1;
    __syncthreads();
    for (int off = 128; off > 0; off >>= 1) {
        if (threadIdx.x < off) {
            r0[threadIdx.x] += r0[threadIdx.x + off];
            r1[threadIdx.x] += r1[threadIdx.x + off];
        }
        __syncthreads();
    }
    float l0 = r0[0] + gb[0], l1 = r1[0] + gb[1];
    float m = fmaxf(l0, l1);
    float e0 = __expf(l0 - m), e1 = __expf(l1 - m);
    float g0 = e0 / (e0 + e1), g1 = e1 / (e0 + e1);
    const float* mr = mo + (size_t)tok * HIDN;
    const float* pr = po + (size_t)tok * HIDN;
    float* orow = out + (size_t)tok * HIDN;
    for (int i = threadIdx.x; i < HIDN; i += 256)
        orow[i] = g0 * mr[i] + g1 * pr[i];
}

// ---------------------------------------------------------------------------
extern "C" void kernel_launch(void* const* d_in, const int* in_sizes, int n_in,
                              void* d_out, int out_size, void* d_ws, size_t ws_size,
                              hipStream_t stream)
{
    const float* X        = (const float*)d_in[0];
    const float* q_a_w    = (const float*)d_in[1];
    const float* q_a_ln_w = (const float*)d_in[2];
    const float* q_b_w    = (const float*)d_in[3];
    const float* kv_a_w   = (const float*)d_in[4];
    const float* kv_a_ln_w= (const float*)d_in[5];
    const float* kv_b_w   = (const float*)d_in[6];
    const float* o_w      = (const float*)d_in[7];
    const float* sp_q_w   = (const float*)d_in[8];
    const float* sp_k_w   = (const float*)d_in[9];
    const float* sp_v_w   = (const float*)d_in[10];
    const float* sp_o_w   = (const float*)d_in[11];
    const float* gate_w   = (const float*)d_in[12];
    const float* gate_b   = (const float*)d_in[13];
    float* out = (float*)d_out;

    // workspace carve (256B aligned) — ~139.5 MB total
    char* p = (char*)d_ws;
    auto alloc = [&](size_t bytes) -> char* {
        char* r = p; p += (bytes + 255) & ~(size_t)255; return r;
    };
    u16* amid      = (u16*)alloc((size_t)NTOK * 3072 * 2);       // bf16 [tok][q_mid|kv_a]
    u16* Xb        = (u16*)alloc((size_t)NTOK * HIDN * 2);
    u16* aw_b      = (u16*)alloc((size_t)3072 * HIDN * 2);       // [q_a_w; kv_a_w]
    u16* q_b_wb    = (u16*)alloc((size_t)NH * DQ * QRANK * 2);
    u16* kv_b_wb   = (u16*)alloc((size_t)NH * 256 * KVRANK * 2);
    u16* o_wb      = (u16*)alloc((size_t)HIDN * HIDN * 2);
    u16* spqkv_wb  = (u16*)alloc((size_t)3 * HIDN * HIDN * 2);   // [spq;spk;spv]
    u16* sp_o_wb   = (u16*)alloc((size_t)HIDN * HIDN * 2);
    u16* qf        = (u16*)alloc((size_t)NTOK * NH * DQ * 2);
    u16* kf        = (u16*)alloc((size_t)NTOK * NH * DQ * 2);
    u16* Vtg       = (u16*)alloc((size_t)NBATCH * NH * 128 * SEQ * 2);
    u16* pq        = (u16*)alloc((size_t)NTOK * HIDN * 2);
    u16* pk        = (u16*)alloc((size_t)NTOK * HIDN * 2);
    // aliases (stream-ordered disjoint lifetimes):
    u16* pvt    = aw_b;          // aw_b dead after amid GEMM; pvt written disp 4
    u16* ctx    = q_b_wb;        // q_b_wb dead after disp 4; ctx written disp 6
    u16* p_ctx  = spqkv_wb;      // spqkv_wb dead after disp 4; written disp 6
    float* patout = (float*)qf;  // qf+kf (25.2MB contig) dead after flash; 16.8MB

    dim3 blk(256);

    // ---- 1. single fused cast dispatch ----
    CastArgs ca;
    const float* srcs[10] = {X, q_a_w, kv_a_w, q_b_w, kv_b_w, o_w,
                             sp_q_w, sp_k_w, sp_v_w, sp_o_w};
    u16* dsts[10] = {Xb, aw_b, aw_b + (size_t)QRANK * HIDN, q_b_wb, kv_b_wb, o_wb,
                     spqkv_wb, spqkv_wb + (size_t)HIDN * HIDN,
                     spqkv_wb + (size_t)2 * HIDN * HIDN, sp_o_wb};
    int ns[10] = {NTOK * HIDN, QRANK * HIDN, 1536 * HIDN, NH * DQ * QRANK,
                  NH * 256 * KVRANK, HIDN * HIDN, HIDN * HIDN, HIDN * HIDN,
                  HIDN * HIDN, HIDN * HIDN};
    int cum = 0;
    for (int i = 0; i < 10; ++i) {
        ca.s[i] = srcs[i]; ca.d[i] = dsts[i];
        ca.cum[i] = cum; cum += ns[i] / 8;
    }
    ca.cum[10] = cum;
    cast_all<<<dim3((cum + 255) / 256), blk, 0, stream>>>(ca, cum);

    // ---- 2. fused q_a + kv_a projection -> amid bf16 [tok][3072] ----
    {
        GemmArgs ga = {};
        ga.nseg = 1;
        ga.seg[0] = {Xb, aw_b, nullptr, amid, nullptr, nullptr,
                     HIDN, HIDN, 3072, 5, 0};
        gemm_multi<<<dim3(24, 16), blk, 0, stream>>>(ga);
    }

    // ---- 3. fused rmsnorm (q_mid rows then kv_lora rows), in place ----
    rmsnorm_fused<<<dim3(2 * NTOK), blk, 0, stream>>>(amid, q_a_ln_w, kv_a_ln_w);

    // ---- 4. mega GEMM: q_b | kv_b | sp_qkv  (104 x 16 = 1664 blocks) ----
    {
        GemmArgs ga = {};
        ga.nseg = 3;
        ga.seg[0] = {amid, q_b_wb, nullptr, qf, nullptr, nullptr,
                     QRANK, 3072, 0, 1, 0};
        ga.seg[1] = {amid + QRANK, kv_b_wb, nullptr, kf, Vtg, nullptr,
                     KVRANK, 3072, 0, 3, 24};
        ga.seg[2] = {Xb, spqkv_wb, nullptr, pq, pk, pvt,
                     HIDN, HIDN, 0, 4, 56};
        gemm_multi<<<dim3(104, 16), blk, 0, stream>>>(ga);
    }

    // ---- 5. fused rope (q in place; k_pe -> kf) ----
    rope_fused<<<dim3(8192), blk, 0, stream>>>(qf, amid, kf);

    // ---- 6. fused dual flash attention (1024 blocks, XCD-swizzled) ----
    flash_fused<<<dim3(NH, 32, NBATCH), blk, 0, stream>>>(
        qf, kf, Vtg, ctx, pq, pk, pvt, p_ctx,
        1.0f / sqrtf((float)DQ), 1.0f / sqrtf(128.0f));

    // ---- 7. fused o-proj + sp_o-proj (512 blocks) ----
    {
        GemmArgs ga = {};
        ga.nseg = 2;
        ga.seg[0] = {ctx, o_wb, out, nullptr, nullptr, nullptr,
                     HIDN, HIDN, HIDN, 0, 0};
        ga.seg[1] = {p_ctx, sp_o_wb, patout, nullptr, nullptr, nullptr,
                     HIDN, HIDN, HIDN, 0, 16};
        gemm_multi<<<dim3(32, 16), blk, 0, stream>>>(ga);
    }

    // ---- 8. gate + combine ----
    gate_combine<<<dim3(NTOK), blk, 0, stream>>>(X, gate_w, gate_b, out, patout, out);
}